// Round 1
// baseline (865.312 us; speedup 1.0000x reference)
//
#include <hip/hip_runtime.h>
#include <stdint.h>

#define B_ 32
#define T_ 4096
#define D_ 256
#define S_ 8
#define ITERS_ 3
#define SCALE_ 0.0625f   // 256^-0.5
#define EPS_ 1e-8f
#define NCH 16
#define CHUNK (T_/NCH)   // 256

typedef short short8 __attribute__((ext_vector_type(8)));
typedef float f32x4 __attribute__((ext_vector_type(4)));

__device__ __forceinline__ uint32_t f2bf1(float x){
  union { float f; uint32_t u; } c; c.f = x;
  return (c.u + 0x7fffu + ((c.u >> 16) & 1u)) >> 16;
}
__device__ __forceinline__ uint32_t pack2bf(float a, float b){
  return f2bf1(a) | (f2bf1(b) << 16);
}
__device__ __forceinline__ float bflo(uint32_t u){ union{uint32_t u;float f;} c; c.u = u << 16; return c.f; }
__device__ __forceinline__ float bfhi(uint32_t u){ union{uint32_t u;float f;} c; c.u = u & 0xffff0000u; return c.f; }

// ---------------- init slots: mu + exp(logsigma)*noise -> d_out ----------------
__global__ void k_init(const float* __restrict__ mu, const float* __restrict__ ls,
                       const float* __restrict__ noise, float* __restrict__ slots){
  int i = blockIdx.x * 256 + threadIdx.x;      // 65536 total
  int d = i & 255;
  slots[i] = mu[d] + __expf(ls[d]) * noise[i];
}

// ---------------- W transpose+convert: Wt[n][k] bf16, n<256 = Wk col, else Wv ----------------
__global__ void k_wconv(const float* __restrict__ Wk, const float* __restrict__ Wv,
                        uint16_t* __restrict__ Wt){
  int n = blockIdx.x;       // 0..511
  int k = threadIdx.x;      // 0..255
  float v = (n < 256) ? Wk[k*256 + n] : Wv[k*256 + (n - 256)];
  Wt[n*256 + k] = (uint16_t)f2bf1(v);
}

// ---------------- projection GEMM: [131072,256]x[256,512] -> K,V bf16 ----------------
#define PPITCH 40   // bf16 elems per LDS staging row (80 B = 5*16, balanced banks)
__global__ __launch_bounds__(256) void k_proj(const float* __restrict__ X,
                                              const uint16_t* __restrict__ Wt,
                                              uint16_t* __restrict__ Kp,
                                              uint16_t* __restrict__ Vp){
  __shared__ __align__(16) uint16_t As[128*PPITCH];
  __shared__ __align__(16) uint16_t Bs[128*PPITCH];
  __shared__ __align__(16) uint16_t Cs[128*128];
  int bid = blockIdx.x;
  int x = bid & 7, j = bid >> 3;
  int tau = 512*x + j;              // bijective tile id; groups of 4 share A, same XCD
  int mt = tau >> 2;                // 0..1023
  int nt = tau & 3;                 // 0..3
  int m0 = mt * 128;
  int n0 = nt * 128;
  int tid = threadIdx.x;
  int lane = tid & 63, wid = tid >> 6;
  int wm = wid >> 1, wn = wid & 1;
  int rsel = lane & 15, g = lane >> 4;

  f32x4 acc[4][4];
  for (int a = 0; a < 4; ++a)
    for (int b = 0; b < 4; ++b)
      acc[a][b] = (f32x4){0.f,0.f,0.f,0.f};

  for (int ks = 0; ks < 8; ++ks){
    int k0 = ks*32;
    // stage A (fp32 -> bf16): 128 rows x 32 k
    #pragma unroll
    for (int i = 0; i < 2; ++i){
      int task = i*256 + tid;              // 0..511
      int row = task >> 2, seg = task & 3;
      const float* gp = X + (size_t)(m0 + row)*256 + k0 + seg*8;
      float4 a = *(const float4*)gp;
      float4 b = *(const float4*)(gp + 4);
      uint4 w;
      w.x = pack2bf(a.x, a.y); w.y = pack2bf(a.z, a.w);
      w.z = pack2bf(b.x, b.y); w.w = pack2bf(b.z, b.w);
      *(uint4*)&As[row*PPITCH + seg*8] = w;
    }
    // stage B (bf16 passthrough)
    #pragma unroll
    for (int i = 0; i < 2; ++i){
      int task = i*256 + tid;
      int row = task >> 2, seg = task & 3;
      uint4 v = *(const uint4*)(Wt + (size_t)(n0 + row)*256 + k0 + seg*8);
      *(uint4*)&Bs[row*PPITCH + seg*8] = v;
    }
    __syncthreads();
    short8 af[4], bfr[4];
    #pragma unroll
    for (int t = 0; t < 4; ++t)
      af[t] = *(const short8*)&As[(wm*64 + t*16 + rsel)*PPITCH + g*8];
    #pragma unroll
    for (int t = 0; t < 4; ++t)
      bfr[t] = *(const short8*)&Bs[(wn*64 + t*16 + rsel)*PPITCH + g*8];
    #pragma unroll
    for (int a = 0; a < 4; ++a)
      #pragma unroll
      for (int b = 0; b < 4; ++b)
        acc[a][b] = __builtin_amdgcn_mfma_f32_16x16x32_bf16(af[a], bfr[b], acc[a][b], 0, 0, 0);
    __syncthreads();
  }
  // epilogue: acc -> Cs (bf16) -> coalesced global
  #pragma unroll
  for (int a = 0; a < 4; ++a)
    #pragma unroll
    for (int b = 0; b < 4; ++b)
      #pragma unroll
      for (int r = 0; r < 4; ++r){
        int mrow = wm*64 + a*16 + g*4 + r;
        int ncol = wn*64 + b*16 + rsel;
        Cs[mrow*128 + ncol] = (uint16_t)f2bf1(acc[a][b][r]);
      }
  __syncthreads();
  uint16_t* outp = (n0 < 256) ? Kp : Vp;
  int nbase = n0 & 255;
  #pragma unroll
  for (int i = 0; i < 4; ++i){
    int task = i*256 + tid;            // 0..1023
    int row = task >> 3, seg = task & 7;
    uint4 v = *(uint4*)&Cs[row*128 + seg*16];
    *(uint4*)&outp[(size_t)(m0 + row)*256 + nbase + seg*16] = v;
  }
}

// ---------------- per-iter: LN(slots) @ Wq * SCALE -> q bf16 ----------------
__global__ __launch_bounds__(256) void k_qproj(const float* __restrict__ slots,
                                               const float* __restrict__ Wq,
                                               const float* __restrict__ ng,
                                               const float* __restrict__ nb,
                                               uint16_t* __restrict__ qbf){
  __shared__ float sn[256];
  __shared__ float red[8];
  int row = blockIdx.x;            // 0..255 (= b*8+s)
  int tid = threadIdx.x;
  int lane = tid & 63, wid = tid >> 6;
  float xv = slots[row*256 + tid];
  float s1 = xv, s2 = xv*xv;
  #pragma unroll
  for (int d = 32; d; d >>= 1){ s1 += __shfl_down(s1, d, 64); s2 += __shfl_down(s2, d, 64); }
  if (lane == 0){ red[wid] = s1; red[4 + wid] = s2; }
  __syncthreads();
  float mu = (red[0]+red[1]+red[2]+red[3]) * (1.f/256.f);
  float ms = (red[4]+red[5]+red[6]+red[7]) * (1.f/256.f);
  float rstd = rsqrtf(ms - mu*mu + 1e-5f);
  sn[tid] = (xv - mu)*rstd*ng[tid] + nb[tid];
  __syncthreads();
  float acc = 0.f;
  for (int d = 0; d < 256; ++d) acc += sn[d] * Wq[d*256 + tid];
  qbf[row*256 + tid] = (uint16_t)f2bf1(acc * SCALE_);
}

// ---------------- per-iter: fused dots->softmax(S)->unnorm PV accumulate ----------------
__global__ __launch_bounds__(256) void k_attn(const uint16_t* __restrict__ qbf,
                                              const uint16_t* __restrict__ Kp,
                                              const uint16_t* __restrict__ Vp,
                                              float* __restrict__ upd_part,
                                              float* __restrict__ sum_part){
  __shared__ __align__(16) uint16_t qs[16*264];   // padded pitch 264 bf16 (528 B)
  __shared__ __align__(16) uint16_t Ks[64*264];
  __shared__ __align__(16) uint32_t attp[64*4];   // packed bf16 attn, 4 dwords (8 s) per t
  __shared__ float red[8*256];
  __shared__ float ssum[8];
  int bid = blockIdx.x;
  int b = bid >> 4, ch = bid & 15;
  int tid = threadIdx.x, lane = tid & 63, wid = tid >> 6;
  // stage q into padded LDS, zero pad rows 8..15
  {
    const uint32_t* qg = (const uint32_t*)(qbf + (size_t)b*2048);
    uint32_t* qd = (uint32_t*)qs;
    #pragma unroll
    for (int i = 0; i < 4; ++i){
      int idx = i*256 + tid;              // dword 0..1023
      int s = idx >> 7, c = idx & 127;
      qd[s*132 + c] = qg[idx];
    }
    #pragma unroll
    for (int i = 0; i < 5; ++i){
      int idx = i*256 + tid;
      if (idx < 1056) qd[8*132 + idx] = 0u;
    }
  }
  if (tid < 8) ssum[tid] = 0.f;
  __syncthreads();
  // q fragments in registers (A operand, reused all subtiles)
  short8 aq[8];
  {
    int rs = lane & 15, g = lane >> 4;
    const char* qb = (const char*)qs;
    #pragma unroll
    for (int kk = 0; kk < 8; ++kk)
      aq[kk] = *(const short8*)(qb + rs*528 + kk*64 + g*16);
  }
  float upd[8][4];
  #pragma unroll
  for (int s = 0; s < 8; ++s){ upd[s][0]=0.f; upd[s][1]=0.f; upd[s][2]=0.f; upd[s][3]=0.f; }
  float sp[4] = {0.f,0.f,0.f,0.f};
  int dd = lane * 4;       // PV: this lane's d-quad
  int tq = wid;            // PV: this wave's t-quarter

  for (int st = 0; st < 4; ++st){
    int t0 = ch*CHUNK + st*64;
    // stage K tile 64 x 256 bf16 into padded LDS
    {
      const char* kg = (const char*)Kp + ((size_t)(b*T_ + t0) << 9);
      char* kd = (char*)Ks;
      #pragma unroll
      for (int i = 0; i < 8; ++i){
        int task = i*256 + tid;
        int row = task >> 5, seg = task & 31;
        uint4 v = *(const uint4*)(kg + (row << 9) + (seg << 4));
        *(uint4*)(kd + row*528 + seg*16) = v;
      }
    }
    __syncthreads();
    // dots[s][t] via MFMA: wave wid owns t-tile [wid*16, +16)
    f32x4 dot = (f32x4){0.f,0.f,0.f,0.f};
    int col = lane & 15, g = lane >> 4;
    {
      const char* kb = (const char*)Ks + (wid*16 + col)*528 + g*16;
      #pragma unroll
      for (int kk = 0; kk < 8; ++kk){
        short8 bf = *(const short8*)(kb + kk*64);
        dot = __builtin_amdgcn_mfma_f32_16x16x32_bf16(aq[kk], bf, dot, 0, 0, 0);
      }
    }
    // softmax over s (rows): lanes g=0 hold s0-3, g=1 hold s4-7 (rows 8-15 = zero pad, unused)
    float x0 = dot[0], x1 = dot[1], x2 = dot[2], x3 = dot[3];
    float y0 = __shfl_xor(x0, 16, 64), y1 = __shfl_xor(x1, 16, 64);
    float y2 = __shfl_xor(x2, 16, 64), y3 = __shfl_xor(x3, 16, 64);
    float m = fmaxf(fmaxf(fmaxf(x0,x1), fmaxf(x2,x3)), fmaxf(fmaxf(y0,y1), fmaxf(y2,y3)));
    float e0 = __expf(x0-m), e1 = __expf(x1-m), e2 = __expf(x2-m), e3 = __expf(x3-m);
    float f0 = __expf(y0-m), f1 = __expf(y1-m), f2 = __expf(y2-m), f3 = __expf(y3-m);
    float inv = 1.f / (e0+e1+e2+e3+f0+f1+f2+f3);
    float p0 = e0*inv + EPS_, p1 = e1*inv + EPS_, p2 = e2*inv + EPS_, p3 = e3*inv + EPS_;
    if (g < 2){
      sp[0] += p0; sp[1] += p1; sp[2] += p2; sp[3] += p3;
      int t = wid*16 + col;
      attp[t*4 + g*2 + 0] = pack2bf(p0, p1);
      attp[t*4 + g*2 + 1] = pack2bf(p2, p3);
    }
    __syncthreads();
    // PV: thread owns d-quad, wave owns t-quarter; V streamed from global (L3)
    {
      const char* vg = (const char*)Vp + ((size_t)(b*T_ + t0) << 9) + (size_t)dd*2;
      #pragma unroll
      for (int tt = 0; tt < 16; ++tt){
        int tl = tq*16 + tt;
        uint2 vv = *(const uint2*)(vg + ((size_t)tl << 9));
        uint4 aa = *(const uint4*)&attp[tl*4];
        float v0 = bflo(vv.x), v1 = bfhi(vv.x), v2 = bflo(vv.y), v3 = bfhi(vv.y);
        float av[8];
        av[0] = bflo(aa.x); av[1] = bfhi(aa.x); av[2] = bflo(aa.y); av[3] = bfhi(aa.y);
        av[4] = bflo(aa.z); av[5] = bfhi(aa.z); av[6] = bflo(aa.w); av[7] = bfhi(aa.w);
        #pragma unroll
        for (int s = 0; s < 8; ++s){
          upd[s][0] = fmaf(av[s], v0, upd[s][0]);
          upd[s][1] = fmaf(av[s], v1, upd[s][1]);
          upd[s][2] = fmaf(av[s], v2, upd[s][2]);
          upd[s][3] = fmaf(av[s], v3, upd[s][3]);
        }
      }
    }
    __syncthreads();
  }
  // reduce upd over the 4 t-quarters into red
  for (int ph = 0; ph < 4; ++ph){
    if (tq == ph){
      #pragma unroll
      for (int s = 0; s < 8; ++s)
        #pragma unroll
        for (int j2 = 0; j2 < 4; ++j2){
          if (ph == 0) red[s*256 + dd + j2]  = upd[s][j2];
          else         red[s*256 + dd + j2] += upd[s][j2];
        }
    }
    __syncthreads();
  }
  {
    float* up = upd_part + (size_t)bid * 2048;
    #pragma unroll
    for (int i = 0; i < 8; ++i) up[i*256 + tid] = red[i*256 + tid];
  }
  // attn sums: reduce sp over 16 t-lanes, accumulate per s
  {
    int col = lane & 15, g = lane >> 4;
    #pragma unroll
    for (int dsh = 1; dsh < 16; dsh <<= 1){
      sp[0] += __shfl_xor(sp[0], dsh, 64); sp[1] += __shfl_xor(sp[1], dsh, 64);
      sp[2] += __shfl_xor(sp[2], dsh, 64); sp[3] += __shfl_xor(sp[3], dsh, 64);
    }
    if (col == 0 && g < 2){
      atomicAdd(&ssum[g*4 + 0], sp[0]);
      atomicAdd(&ssum[g*4 + 1], sp[1]);
      atomicAdd(&ssum[g*4 + 2], sp[2]);
      atomicAdd(&ssum[g*4 + 3], sp[3]);
    }
    __syncthreads();
    if (tid < 8) sum_part[(size_t)bid*8 + tid] = ssum[tid];
  }
}

// ---------------- per-iter: reduce partials, GRU cell, pre-norm MLP residual ----------------
__global__ __launch_bounds__(512) void k_gru_mlp(const float* __restrict__ upd_part,
                                                 const float* __restrict__ sum_part,
                                                 const float* __restrict__ wih,
                                                 const float* __restrict__ whh,
                                                 const float* __restrict__ bih,
                                                 const float* __restrict__ bhh,
                                                 const float* __restrict__ mng,
                                                 const float* __restrict__ mnb,
                                                 const float* __restrict__ w1,
                                                 const float* __restrict__ b1,
                                                 const float* __restrict__ w2,
                                                 const float* __restrict__ b2,
                                                 float* __restrict__ slots){
  __shared__ float u[4][256], h[4][256], rz[4][512], inn[4][256], hnn[4][256];
  __shared__ float s2[4][256], sn[4][256], h1[4][1024];
  __shared__ float sums[4];
  __shared__ float red[16];
  int r0 = blockIdx.x * 4;
  int tid = threadIdx.x;
  if (tid < 4){
    int row = r0 + tid; int b = row >> 3, s = row & 7;
    float acc = 0.f;
    for (int ch = 0; ch < 16; ++ch) acc += sum_part[(size_t)(b*16 + ch)*8 + s];
    sums[tid] = acc;
  }
  float uacc[2];
  #pragma unroll
  for (int i = 0; i < 2; ++i){
    int idx = i*512 + tid; int rr = idx >> 8, d = idx & 255;
    int row = r0 + rr; int b = row >> 3, s = row & 7;
    float acc = 0.f;
    for (int ch = 0; ch < 16; ++ch) acc += upd_part[(size_t)(b*16 + ch)*2048 + s*256 + d];
    uacc[i] = acc;
    h[rr][d] = slots[row*256 + d];
  }
  __syncthreads();
  #pragma unroll
  for (int i = 0; i < 2; ++i){
    int idx = i*512 + tid; int rr = idx >> 8, d = idx & 255;
    u[rr][d] = uacc[i] / sums[rr];
  }
  __syncthreads();
  // r,z gates: sigmoid(gi[:,:512] + gh[:,:512])
  for (int i = 0; i < 4; ++i){
    int task = i*512 + tid; int rr = task >> 9, c = task & 511;
    float acc = bih[c] + bhh[c];
    for (int d = 0; d < 256; ++d)
      acc += u[rr][d]*wih[d*768 + c] + h[rr][d]*whh[d*768 + c];
    rz[rr][c] = 1.f / (1.f + __expf(-acc));
  }
  // inn, hn (separate)
  for (int i = 0; i < 2; ++i){
    int task = i*512 + tid; int rr = task >> 8, c = task & 255;
    float ai = bih[512 + c], ah = bhh[512 + c];
    for (int d = 0; d < 256; ++d){
      ai += u[rr][d]*wih[d*768 + 512 + c];
      ah += h[rr][d]*whh[d*768 + 512 + c];
    }
    inn[rr][c] = ai; hnn[rr][c] = ah;
  }
  __syncthreads();
  // combine
  #pragma unroll
  for (int i = 0; i < 2; ++i){
    int task = i*512 + tid; int rr = task >> 8, c = task & 255;
    float rv = rz[rr][c], zv = rz[rr][256 + c];
    float nv = tanhf(inn[rr][c] + rv*hnn[rr][c]);
    s2[rr][c] = (1.f - zv)*nv + zv*h[rr][c];
  }
  __syncthreads();
  // LN per row (2 waves per row)
  {
    int lane = tid & 63, wid = tid >> 6;
    int rr = wid >> 1, half = wid & 1;
    int d = half*128 + lane*2;
    float a = s2[rr][d], bb = s2[rr][d+1];
    float p1 = a + bb, p2 = a*a + bb*bb;
    #pragma unroll
    for (int dsh = 32; dsh; dsh >>= 1){ p1 += __shfl_down(p1, dsh, 64); p2 += __shfl_down(p2, dsh, 64); }
    if (lane == 0){ red[wid*2] = p1; red[wid*2 + 1] = p2; }
  }
  __syncthreads();
  #pragma unroll
  for (int i = 0; i < 2; ++i){
    int task = i*512 + tid; int rr = task >> 8, c = task & 255;
    float mu = (red[rr*4] + red[rr*4 + 2]) * (1.f/256.f);
    float ms = (red[rr*4 + 1] + red[rr*4 + 3]) * (1.f/256.f);
    float rstd = rsqrtf(ms - mu*mu + 1e-5f);
    sn[rr][c] = (s2[rr][c] - mu)*rstd*mng[c] + mnb[c];
  }
  __syncthreads();
  // MLP hidden
  for (int i = 0; i < 8; ++i){
    int task = i*512 + tid; int rr = task >> 10, jj = task & 1023;
    float acc = b1[jj];
    for (int d = 0; d < 256; ++d) acc += sn[rr][d]*w1[d*1024 + jj];
    h1[rr][jj] = fmaxf(acc, 0.f);
  }
  __syncthreads();
  // MLP out + residual
  #pragma unroll
  for (int i = 0; i < 2; ++i){
    int task = i*512 + tid; int rr = task >> 8, d = task & 255;
    float acc = b2[d];
    for (int jj = 0; jj < 1024; ++jj) acc += h1[rr][jj]*w2[jj*256 + d];
    int row = r0 + rr;
    slots[row*256 + d] = s2[rr][d] + acc;
  }
}

extern "C" void kernel_launch(void* const* d_in, const int* in_sizes, int n_in,
                              void* d_out, int out_size, void* d_ws, size_t ws_size,
                              hipStream_t stream){
  const float* inputs = (const float*)d_in[0];
  const float* mu     = (const float*)d_in[1];
  const float* lsig   = (const float*)d_in[2];
  const float* noise  = (const float*)d_in[3];
  const float* Wq     = (const float*)d_in[4];
  const float* Wk     = (const float*)d_in[5];
  const float* Wv     = (const float*)d_in[6];
  const float* ng     = (const float*)d_in[7];
  const float* nb     = (const float*)d_in[8];
  const float* wih    = (const float*)d_in[9];
  const float* whh    = (const float*)d_in[10];
  const float* bih    = (const float*)d_in[11];
  const float* bhh    = (const float*)d_in[12];
  const float* mng    = (const float*)d_in[13];
  const float* mnb    = (const float*)d_in[14];
  const float* w1     = (const float*)d_in[15];
  const float* b1     = (const float*)d_in[16];
  const float* w2     = (const float*)d_in[17];
  const float* b2     = (const float*)d_in[18];
  float* slots = (float*)d_out;

  char* ws = (char*)d_ws;
  uint16_t* Wt       = (uint16_t*)(ws + 0);            // 512*256*2   = 256 KB
  uint16_t* qbf      = (uint16_t*)(ws + 262144);       // 256*256*2   = 128 KB
  float*    sum_part = (float*)   (ws + 393216);       // 512*8*4     = 16 KB
  float*    upd_part = (float*)   (ws + 409600);       // 512*2048*4  = 4 MB
  uint16_t* Kp       = (uint16_t*)(ws + 8388608);      // 64 MB
  uint16_t* Vp       = (uint16_t*)(ws + 75497472);     // 64 MB (ends ~136 MB)

  hipLaunchKernelGGL(k_init,  dim3(256),  dim3(256), 0, stream, mu, lsig, noise, slots);
  hipLaunchKernelGGL(k_wconv, dim3(512),  dim3(256), 0, stream, Wk, Wv, Wt);
  hipLaunchKernelGGL(k_proj,  dim3(4096), dim3(256), 0, stream, inputs, Wt, Kp, Vp);
  for (int it = 0; it < ITERS_; ++it){
    hipLaunchKernelGGL(k_qproj,   dim3(256), dim3(256), 0, stream, slots, Wq, ng, nb, qbf);
    hipLaunchKernelGGL(k_attn,    dim3(512), dim3(256), 0, stream, qbf, Kp, Vp, upd_part, sum_part);
    hipLaunchKernelGGL(k_gru_mlp, dim3(64),  dim3(512), 0, stream, upd_part, sum_part,
                       wih, whh, bih, bhh, mng, mnb, w1, b1, w2, b2, slots);
  }
}

// Round 3
// 526.522 us; speedup vs baseline: 1.6434x; 1.6434x over previous
//
#include <hip/hip_runtime.h>
#include <stdint.h>

#define B_ 32
#define T_ 4096
#define D_ 256
#define S_ 8
#define ITERS_ 3
#define SCALE_ 0.0625f   // 256^-0.5
#define EPS_ 1e-8f
#define NCH 16
#define CHUNK (T_/NCH)   // 256

typedef short short8 __attribute__((ext_vector_type(8)));
typedef float f32x4 __attribute__((ext_vector_type(4)));

__device__ __forceinline__ uint32_t f2bf1(float x){
  union { float f; uint32_t u; } c; c.f = x;
  return (c.u + 0x7fffu + ((c.u >> 16) & 1u)) >> 16;
}
__device__ __forceinline__ uint32_t pack2bf(float a, float b){
  return f2bf1(a) | (f2bf1(b) << 16);
}
__device__ __forceinline__ float bflo(uint32_t u){ union{uint32_t u;float f;} c; c.u = u << 16; return c.f; }
__device__ __forceinline__ float bfhi(uint32_t u){ union{uint32_t u;float f;} c; c.u = u & 0xffff0000u; return c.f; }

// ---------------- init slots: mu + exp(logsigma)*noise -> d_out ----------------
__global__ void k_init(const float* __restrict__ mu, const float* __restrict__ ls,
                       const float* __restrict__ noise, float* __restrict__ slots){
  int i = blockIdx.x * 256 + threadIdx.x;      // 65536 total
  int d = i & 255;
  slots[i] = mu[d] + __expf(ls[d]) * noise[i];
}

// ---------------- W transpose+convert: Wt[n][k] bf16, n<256 = Wk col, else Wv ----------------
__global__ void k_wconv(const float* __restrict__ Wk, const float* __restrict__ Wv,
                        uint16_t* __restrict__ Wt){
  int n = blockIdx.x;       // 0..511
  int k = threadIdx.x;      // 0..255
  float v = (n < 256) ? Wk[k*256 + n] : Wv[k*256 + (n - 256)];
  Wt[n*256 + k] = (uint16_t)f2bf1(v);
}

// Wq transposed * SCALE -> bf16 [256 n][256 k]
__global__ void k_wq(const float* __restrict__ Wq, uint16_t* __restrict__ Wqt){
  int n = blockIdx.x, k = threadIdx.x;
  Wqt[n*256 + k] = (uint16_t)f2bf1(Wq[k*256 + n] * SCALE_);
}

// Bcat [1024 n][512 k] bf16:
//  n<768:  k<256 -> wih[k][n]; k>=256 -> whh[k-256][n]
//  n>=768: k<256 -> 0;         k>=256 -> whh[k-256][512+(n-768)]
__global__ void k_bcat(const float* __restrict__ wih, const float* __restrict__ whh,
                       uint16_t* __restrict__ Bcat){
  int n = blockIdx.x;      // 0..1023
  int k = threadIdx.x;     // 0..511
  float v;
  if (n < 768) v = (k < 256) ? wih[k*768 + n] : whh[(k-256)*768 + n];
  else         v = (k < 256) ? 0.f            : whh[(k-256)*768 + 512 + (n-768)];
  Bcat[(size_t)n*512 + k] = (uint16_t)f2bf1(v);
}

// bcat bias fp32 [1024]: i<512: bih+bhh; [512,768): bih; [768,1024): bhh[i-256]
__global__ void k_bc(const float* __restrict__ bih, const float* __restrict__ bhh,
                     float* __restrict__ bc){
  int i = blockIdx.x*256 + threadIdx.x;   // 1024
  float v;
  if (i < 512) v = bih[i] + bhh[i];
  else if (i < 768) v = bih[i];
  else v = bhh[i - 256];
  bc[i] = v;
}

// w1t [1024 n][256 k]
__global__ void k_w1t(const float* __restrict__ w1, uint16_t* __restrict__ w1t){
  int n = blockIdx.x, k = threadIdx.x;
  w1t[(size_t)n*256 + k] = (uint16_t)f2bf1(w1[(size_t)k*1024 + n]);
}
// w2t [256 n][1024 k]
__global__ void k_w2t(const float* __restrict__ w2, uint16_t* __restrict__ w2t){
  int n = blockIdx.x, k0 = threadIdx.x;
  #pragma unroll
  for (int j = 0; j < 4; ++j){
    int k = j*256 + k0;
    w2t[(size_t)n*1024 + k] = (uint16_t)f2bf1(w2[(size_t)k*256 + n]);
  }
}

// ---------------- projection GEMM: [131072,256]x[256,512] -> K,V bf16 ----------------
#define PPITCH 40   // bf16 elems per LDS staging row (80 B)
__global__ __launch_bounds__(256) void k_proj(const float* __restrict__ X,
                                              const uint16_t* __restrict__ Wt,
                                              uint16_t* __restrict__ Kp,
                                              uint16_t* __restrict__ Vp){
  __shared__ __align__(16) uint16_t As[128*PPITCH];
  __shared__ __align__(16) uint16_t Bs[128*PPITCH];
  __shared__ __align__(16) uint16_t Cs[128*128];
  int bid = blockIdx.x;
  int x = bid & 7, j = bid >> 3;
  int tau = 512*x + j;              // bijective; groups of 4 share A-panel on one XCD
  int mt = tau >> 2;
  int nt = tau & 3;
  int m0 = mt * 128;
  int n0 = nt * 128;
  int tid = threadIdx.x;
  int lane = tid & 63, wid = tid >> 6;
  int wm = wid >> 1, wn = wid & 1;
  int rsel = lane & 15, g = lane >> 4;

  f32x4 acc[4][4];
  for (int a = 0; a < 4; ++a)
    for (int b = 0; b < 4; ++b)
      acc[a][b] = (f32x4){0.f,0.f,0.f,0.f};

  for (int ks = 0; ks < 8; ++ks){
    int k0 = ks*32;
    #pragma unroll
    for (int i = 0; i < 2; ++i){
      int task = i*256 + tid;
      int row = task >> 2, seg = task & 3;
      const float* gp = X + (size_t)(m0 + row)*256 + k0 + seg*8;
      float4 a = *(const float4*)gp;
      float4 b = *(const float4*)(gp + 4);
      uint4 w;
      w.x = pack2bf(a.x, a.y); w.y = pack2bf(a.z, a.w);
      w.z = pack2bf(b.x, b.y); w.w = pack2bf(b.z, b.w);
      *(uint4*)&As[row*PPITCH + seg*8] = w;
    }
    #pragma unroll
    for (int i = 0; i < 2; ++i){
      int task = i*256 + tid;
      int row = task >> 2, seg = task & 3;
      uint4 v = *(const uint4*)(Wt + (size_t)(n0 + row)*256 + k0 + seg*8);
      *(uint4*)&Bs[row*PPITCH + seg*8] = v;
    }
    __syncthreads();
    short8 af[4], bfr[4];
    #pragma unroll
    for (int t = 0; t < 4; ++t)
      af[t] = *(const short8*)&As[(wm*64 + t*16 + rsel)*PPITCH + g*8];
    #pragma unroll
    for (int t = 0; t < 4; ++t)
      bfr[t] = *(const short8*)&Bs[(wn*64 + t*16 + rsel)*PPITCH + g*8];
    #pragma unroll
    for (int a = 0; a < 4; ++a)
      #pragma unroll
      for (int b = 0; b < 4; ++b)
        acc[a][b] = __builtin_amdgcn_mfma_f32_16x16x32_bf16(af[a], bfr[b], acc[a][b], 0, 0, 0);
    __syncthreads();
  }
  #pragma unroll
  for (int a = 0; a < 4; ++a)
    #pragma unroll
    for (int b = 0; b < 4; ++b)
      #pragma unroll
      for (int r = 0; r < 4; ++r){
        int mrow = wm*64 + a*16 + g*4 + r;
        int ncol = wn*64 + b*16 + rsel;
        Cs[mrow*128 + ncol] = (uint16_t)f2bf1(acc[a][b][r]);
      }
  __syncthreads();
  uint16_t* outp = (n0 < 256) ? Kp : Vp;
  int nbase = n0 & 255;
  #pragma unroll
  for (int i = 0; i < 4; ++i){
    int task = i*256 + tid;
    int row = task >> 3, seg = task & 7;
    uint4 v = *(uint4*)&Cs[row*128 + seg*16];
    *(uint4*)&outp[(size_t)(m0 + row)*256 + nbase + seg*16] = v;
  }
}

// ---------------- generic small GEMM: C[M,N] = A[M,K](bf16) x B[N,K](bf16)^T ----------------
// MODE 0: Cf = acc                      (fp32)
// MODE 1: Cb = bf16(relu(acc+bias[n]))
// MODE 2: Cf = acc + bias[n] + resid    (fp32)
// MODE 3: Cb = bf16(acc)
#define GPIT 40
template<int MODE>
__global__ __launch_bounds__(256) void k_gemm64(const uint16_t* __restrict__ A,
                                                const uint16_t* __restrict__ Bm,
                                                const float* __restrict__ bias,
                                                const float* __restrict__ resid,
                                                float* __restrict__ Cf,
                                                uint16_t* __restrict__ Cb,
                                                int N, int K){
  __shared__ __align__(16) uint16_t As[64*GPIT];
  __shared__ __align__(16) uint16_t Bs[64*GPIT];
  int m0 = blockIdx.y * 64, n0 = blockIdx.x * 64;
  int tid = threadIdx.x, lane = tid & 63, wid = tid >> 6;
  int wm = wid >> 1, wn = wid & 1;
  int rsel = lane & 15, g = lane >> 4;
  f32x4 acc[2][2];
  #pragma unroll
  for (int a = 0; a < 2; ++a)
    #pragma unroll
    for (int b = 0; b < 2; ++b)
      acc[a][b] = (f32x4){0.f,0.f,0.f,0.f};
  int row_s = tid >> 2, seg = tid & 3;
  for (int k0 = 0; k0 < K; k0 += 32){
    *(uint4*)&As[row_s*GPIT + seg*8] = *(const uint4*)(A  + (size_t)(m0+row_s)*K + k0 + seg*8);
    *(uint4*)&Bs[row_s*GPIT + seg*8] = *(const uint4*)(Bm + (size_t)(n0+row_s)*K + k0 + seg*8);
    __syncthreads();
    short8 af[2], bfr[2];
    #pragma unroll
    for (int t = 0; t < 2; ++t)
      af[t]  = *(const short8*)&As[(wm*32 + t*16 + rsel)*GPIT + g*8];
    #pragma unroll
    for (int t = 0; t < 2; ++t)
      bfr[t] = *(const short8*)&Bs[(wn*32 + t*16 + rsel)*GPIT + g*8];
    #pragma unroll
    for (int a = 0; a < 2; ++a)
      #pragma unroll
      for (int b = 0; b < 2; ++b)
        acc[a][b] = __builtin_amdgcn_mfma_f32_16x16x32_bf16(af[a], bfr[b], acc[a][b], 0, 0, 0);
    __syncthreads();
  }
  #pragma unroll
  for (int a = 0; a < 2; ++a)
    #pragma unroll
    for (int b = 0; b < 2; ++b)
      #pragma unroll
      for (int r = 0; r < 4; ++r){
        int mrow = m0 + wm*32 + a*16 + g*4 + r;
        int ncol = n0 + wn*32 + b*16 + rsel;
        float v = acc[a][b][r];
        if (MODE == 0) Cf[(size_t)mrow*N + ncol] = v;
        if (MODE == 1) Cb[(size_t)mrow*N + ncol] = (uint16_t)f2bf1(fmaxf(v + bias[ncol], 0.f));
        if (MODE == 2) Cf[(size_t)mrow*N + ncol] = v + bias[ncol] + resid[(size_t)mrow*N + ncol];
        if (MODE == 3) Cb[(size_t)mrow*N + ncol] = (uint16_t)f2bf1(v);
      }
}

// ---------------- LN(src row) * g + b -> bf16 dst ----------------
__global__ __launch_bounds__(256) void k_ln(const float* __restrict__ src,
                                            const float* __restrict__ gg,
                                            const float* __restrict__ bb,
                                            uint16_t* __restrict__ dst){
  __shared__ float red[8];
  int row = blockIdx.x, tid = threadIdx.x;
  int lane = tid & 63, wid = tid >> 6;
  float xv = src[row*256 + tid];
  float s1 = xv, s2 = xv*xv;
  #pragma unroll
  for (int d = 32; d; d >>= 1){ s1 += __shfl_down(s1, d, 64); s2 += __shfl_down(s2, d, 64); }
  if (lane == 0){ red[wid] = s1; red[4 + wid] = s2; }
  __syncthreads();
  float mu = (red[0]+red[1]+red[2]+red[3]) * (1.f/256.f);
  float ms = (red[4]+red[5]+red[6]+red[7]) * (1.f/256.f);
  float rstd = rsqrtf(ms - mu*mu + 1e-5f);
  dst[row*256 + tid] = (uint16_t)f2bf1((xv - mu)*rstd*gg[tid] + bb[tid]);
}

// ---------------- reduce attn partials -> Acat bf16 [256][512] = [u | h] ----------------
__global__ __launch_bounds__(256) void k_gru_pre(const float* __restrict__ upd_part,
                                                 const float* __restrict__ sum_part,
                                                 const float* __restrict__ slots,
                                                 uint16_t* __restrict__ Acat){
  int row = blockIdx.x;           // 0..255 = b*8+s
  int b = row >> 3, s = row & 7;
  int d = threadIdx.x;
  float sum = 0.f;
  #pragma unroll
  for (int ch = 0; ch < 16; ++ch) sum += sum_part[(size_t)(b*16 + ch)*8 + s];
  float acc = 0.f;
  #pragma unroll
  for (int ch = 0; ch < 16; ++ch) acc += upd_part[(size_t)(b*16 + ch)*2048 + s*256 + d];
  Acat[(size_t)row*512 + d]       = (uint16_t)f2bf1(acc / sum);
  Acat[(size_t)row*512 + 256 + d] = (uint16_t)f2bf1(slots[row*256 + d]);
}

// ---------------- GRU combine + LN -> s2f fp32, snb bf16 ----------------
__global__ __launch_bounds__(256) void k_combine(const float* __restrict__ G,
                                                 const float* __restrict__ bc,
                                                 const float* __restrict__ slots,
                                                 const float* __restrict__ mng,
                                                 const float* __restrict__ mnb,
                                                 float* __restrict__ s2f,
                                                 uint16_t* __restrict__ snb){
  __shared__ float red[8];
  int row = blockIdx.x, c = threadIdx.x;
  int lane = c & 63, wid = c >> 6;
  const float* Gr = G + (size_t)row*1024;
  float r  = 1.f / (1.f + __expf(-(Gr[c]       + bc[c])));
  float z  = 1.f / (1.f + __expf(-(Gr[256 + c] + bc[256 + c])));
  float Gn = Gr[512 + c], Gh = Gr[768 + c];
  float nn = tanhf((Gn - Gh + bc[512 + c]) + r*(Gh + bc[768 + c]));
  float hv = slots[row*256 + c];
  float s2 = (1.f - z)*nn + z*hv;
  s2f[row*256 + c] = s2;
  float p1 = s2, p2 = s2*s2;
  #pragma unroll
  for (int d = 32; d; d >>= 1){ p1 += __shfl_down(p1, d, 64); p2 += __shfl_down(p2, d, 64); }
  if (lane == 0){ red[wid] = p1; red[4 + wid] = p2; }
  __syncthreads();
  float mu = (red[0]+red[1]+red[2]+red[3]) * (1.f/256.f);
  float ms = (red[4]+red[5]+red[6]+red[7]) * (1.f/256.f);
  float rstd = rsqrtf(ms - mu*mu + 1e-5f);
  snb[row*256 + c] = (uint16_t)f2bf1((s2 - mu)*rstd*mng[c] + mnb[c]);
}

// ---------------- per-iter: fused dots->softmax(S)->unnorm PV accumulate ----------------
__global__ __launch_bounds__(256) void k_attn(const uint16_t* __restrict__ qbf,
                                              const uint16_t* __restrict__ Kp,
                                              const uint16_t* __restrict__ Vp,
                                              float* __restrict__ upd_part,
                                              float* __restrict__ sum_part){
  __shared__ __align__(16) uint16_t qs[16*264];
  __shared__ __align__(16) uint16_t Ks[64*264];
  __shared__ __align__(16) uint32_t attp[64*4];
  __shared__ float red[8*256];
  __shared__ float ssum[8];
  int bid = blockIdx.x;
  int b = bid >> 4, ch = bid & 15;
  int tid = threadIdx.x, lane = tid & 63, wid = tid >> 6;
  {
    const uint32_t* qg = (const uint32_t*)(qbf + (size_t)b*2048);
    uint32_t* qd = (uint32_t*)qs;
    #pragma unroll
    for (int i = 0; i < 4; ++i){
      int idx = i*256 + tid;
      int s = idx >> 7, c = idx & 127;
      qd[s*132 + c] = qg[idx];
    }
    #pragma unroll
    for (int i = 0; i < 5; ++i){
      int idx = i*256 + tid;
      if (idx < 1056) qd[8*132 + idx] = 0u;
    }
  }
  if (tid < 8) ssum[tid] = 0.f;
  __syncthreads();
  short8 aq[8];
  {
    int rs = lane & 15, g = lane >> 4;
    const char* qb = (const char*)qs;
    #pragma unroll
    for (int kk = 0; kk < 8; ++kk)
      aq[kk] = *(const short8*)(qb + rs*528 + kk*64 + g*16);
  }
  float upd[8][4];
  #pragma unroll
  for (int s = 0; s < 8; ++s){ upd[s][0]=0.f; upd[s][1]=0.f; upd[s][2]=0.f; upd[s][3]=0.f; }
  float sp[4] = {0.f,0.f,0.f,0.f};
  int dd = lane * 4;
  int tq = wid;

  for (int st = 0; st < 4; ++st){
    int t0 = ch*CHUNK + st*64;
    {
      const char* kg = (const char*)Kp + ((size_t)(b*T_ + t0) << 9);
      char* kd = (char*)Ks;
      #pragma unroll
      for (int i = 0; i < 8; ++i){
        int task = i*256 + tid;
        int row = task >> 5, seg = task & 31;
        uint4 v = *(const uint4*)(kg + (row << 9) + (seg << 4));
        *(uint4*)(kd + row*528 + seg*16) = v;
      }
    }
    __syncthreads();
    f32x4 dot = (f32x4){0.f,0.f,0.f,0.f};
    int col = lane & 15, g = lane >> 4;
    {
      const char* kb = (const char*)Ks + (wid*16 + col)*528 + g*16;
      #pragma unroll
      for (int kk = 0; kk < 8; ++kk){
        short8 bf = *(const short8*)(kb + kk*64);
        dot = __builtin_amdgcn_mfma_f32_16x16x32_bf16(aq[kk], bf, dot, 0, 0, 0);
      }
    }
    float x0 = dot[0], x1 = dot[1], x2 = dot[2], x3 = dot[3];
    float y0 = __shfl_xor(x0, 16, 64), y1 = __shfl_xor(x1, 16, 64);
    float y2 = __shfl_xor(x2, 16, 64), y3 = __shfl_xor(x3, 16, 64);
    float m = fmaxf(fmaxf(fmaxf(x0,x1), fmaxf(x2,x3)), fmaxf(fmaxf(y0,y1), fmaxf(y2,y3)));
    float e0 = __expf(x0-m), e1 = __expf(x1-m), e2 = __expf(x2-m), e3 = __expf(x3-m);
    float f0 = __expf(y0-m), f1 = __expf(y1-m), f2 = __expf(y2-m), f3 = __expf(y3-m);
    float inv = 1.f / (e0+e1+e2+e3+f0+f1+f2+f3);
    float p0 = e0*inv + EPS_, p1 = e1*inv + EPS_, p2 = e2*inv + EPS_, p3 = e3*inv + EPS_;
    if (g < 2){
      sp[0] += p0; sp[1] += p1; sp[2] += p2; sp[3] += p3;
      int t = wid*16 + col;
      attp[t*4 + g*2 + 0] = pack2bf(p0, p1);
      attp[t*4 + g*2 + 1] = pack2bf(p2, p3);
    }
    __syncthreads();
    {
      const char* vg = (const char*)Vp + ((size_t)(b*T_ + t0) << 9) + (size_t)dd*2;
      #pragma unroll
      for (int tt = 0; tt < 16; ++tt){
        int tl = tq*16 + tt;
        uint2 vv = *(const uint2*)(vg + ((size_t)tl << 9));
        uint4 aa = *(const uint4*)&attp[tl*4];
        float v0 = bflo(vv.x), v1 = bfhi(vv.x), v2 = bflo(vv.y), v3 = bfhi(vv.y);
        float av[8];
        av[0] = bflo(aa.x); av[1] = bfhi(aa.x); av[2] = bflo(aa.y); av[3] = bfhi(aa.y);
        av[4] = bflo(aa.z); av[5] = bfhi(aa.z); av[6] = bflo(aa.w); av[7] = bfhi(aa.w);
        #pragma unroll
        for (int s = 0; s < 8; ++s){
          upd[s][0] = fmaf(av[s], v0, upd[s][0]);
          upd[s][1] = fmaf(av[s], v1, upd[s][1]);
          upd[s][2] = fmaf(av[s], v2, upd[s][2]);
          upd[s][3] = fmaf(av[s], v3, upd[s][3]);
        }
      }
    }
    __syncthreads();
  }
  for (int ph = 0; ph < 4; ++ph){
    if (tq == ph){
      #pragma unroll
      for (int s = 0; s < 8; ++s)
        #pragma unroll
        for (int j2 = 0; j2 < 4; ++j2){
          if (ph == 0) red[s*256 + dd + j2]  = upd[s][j2];
          else         red[s*256 + dd + j2] += upd[s][j2];
        }
    }
    __syncthreads();
  }
  {
    float* up = upd_part + (size_t)bid * 2048;
    #pragma unroll
    for (int i = 0; i < 8; ++i) up[i*256 + tid] = red[i*256 + tid];
  }
  {
    int col = lane & 15, g = lane >> 4;
    #pragma unroll
    for (int dsh = 1; dsh < 16; dsh <<= 1){
      sp[0] += __shfl_xor(sp[0], dsh, 64); sp[1] += __shfl_xor(sp[1], dsh, 64);
      sp[2] += __shfl_xor(sp[2], dsh, 64); sp[3] += __shfl_xor(sp[3], dsh, 64);
    }
    if (col == 0 && g < 2){
      atomicAdd(&ssum[g*4 + 0], sp[0]);
      atomicAdd(&ssum[g*4 + 1], sp[1]);
      atomicAdd(&ssum[g*4 + 2], sp[2]);
      atomicAdd(&ssum[g*4 + 3], sp[3]);
    }
    __syncthreads();
    if (tid < 8) sum_part[(size_t)bid*8 + tid] = ssum[tid];
  }
}

extern "C" void kernel_launch(void* const* d_in, const int* in_sizes, int n_in,
                              void* d_out, int out_size, void* d_ws, size_t ws_size,
                              hipStream_t stream){
  const float* inputs = (const float*)d_in[0];
  const float* mu     = (const float*)d_in[1];
  const float* lsig   = (const float*)d_in[2];
  const float* noise  = (const float*)d_in[3];
  const float* Wq     = (const float*)d_in[4];
  const float* Wk     = (const float*)d_in[5];
  const float* Wv     = (const float*)d_in[6];
  const float* ng     = (const float*)d_in[7];
  const float* nb     = (const float*)d_in[8];
  const float* wih    = (const float*)d_in[9];
  const float* whh    = (const float*)d_in[10];
  const float* bih    = (const float*)d_in[11];
  const float* bhh    = (const float*)d_in[12];
  const float* mng    = (const float*)d_in[13];
  const float* mnb    = (const float*)d_in[14];
  const float* w1     = (const float*)d_in[15];
  const float* b1     = (const float*)d_in[16];
  const float* w2     = (const float*)d_in[17];
  const float* b2     = (const float*)d_in[18];
  float* slots = (float*)d_out;

  char* ws = (char*)d_ws;
  uint16_t* Wt       = (uint16_t*)(ws + 0);            // 256 KB
  uint16_t* qbf      = (uint16_t*)(ws + 0x40000);      // 128 KB
  float*    sum_part = (float*)   (ws + 0x60000);      // 16 KB
  float*    upd_part = (float*)   (ws + 0x64000);      // 4 MB
  uint16_t* Wqt      = (uint16_t*)(ws + 0x480000);     // 128 KB
  uint16_t* Bcat     = (uint16_t*)(ws + 0x4A0000);     // 1 MB
  uint16_t* w1t      = (uint16_t*)(ws + 0x5A0000);     // 512 KB
  uint16_t* w2t      = (uint16_t*)(ws + 0x620000);     // 512 KB
  float*    bc       = (float*)   (ws + 0x6A0000);     // 4 KB
  uint16_t* Acat     = (uint16_t*)(ws + 0x6B0000);     // 256 KB
  float*    G        = (float*)   (ws + 0x6F0000);     // 1 MB
  uint16_t* snb      = (uint16_t*)(ws + 0x7F0000);     // 128 KB
  float*    s2f      = (float*)   (ws + 0x810000);     // 256 KB
  uint16_t* h1b      = (uint16_t*)(ws + 0x850000);     // 512 KB
  uint16_t* lnb      = (uint16_t*)(ws + 0x8D0000);     // 128 KB
  uint16_t* Kp       = (uint16_t*)(ws + 0x1000000);    // 64 MB
  uint16_t* Vp       = (uint16_t*)(ws + 0x5000000);    // 64 MB (ends 144 MB)

  hipLaunchKernelGGL(k_init,  dim3(256),  dim3(256), 0, stream, mu, lsig, noise, slots);
  hipLaunchKernelGGL(k_wconv, dim3(512),  dim3(256), 0, stream, Wk, Wv, Wt);
  hipLaunchKernelGGL(k_wq,    dim3(256),  dim3(256), 0, stream, Wq, Wqt);
  hipLaunchKernelGGL(k_bcat,  dim3(1024), dim3(512), 0, stream, wih, whh, Bcat);
  hipLaunchKernelGGL(k_bc,    dim3(4),    dim3(256), 0, stream, bih, bhh, bc);
  hipLaunchKernelGGL(k_w1t,   dim3(1024), dim3(256), 0, stream, w1, w1t);
  hipLaunchKernelGGL(k_w2t,   dim3(256),  dim3(256), 0, stream, w2, w2t);
  hipLaunchKernelGGL(k_proj,  dim3(4096), dim3(256), 0, stream, inputs, Wt, Kp, Vp);

  for (int it = 0; it < ITERS_; ++it){
    hipLaunchKernelGGL(k_ln,        dim3(256), dim3(256), 0, stream, slots, ng, nb, lnb);
    hipLaunchKernelGGL(k_gemm64<3>, dim3(4,4),  dim3(256), 0, stream, lnb, Wqt,
                       (const float*)nullptr, (const float*)nullptr, (float*)nullptr, qbf, 256, 256);
    hipLaunchKernelGGL(k_attn,      dim3(512), dim3(256), 0, stream, qbf, Kp, Vp, upd_part, sum_part);
    hipLaunchKernelGGL(k_gru_pre,   dim3(256), dim3(256), 0, stream, upd_part, sum_part, slots, Acat);
    hipLaunchKernelGGL(k_gemm64<0>, dim3(16,4), dim3(256), 0, stream, Acat, Bcat,
                       (const float*)nullptr, (const float*)nullptr, G, (uint16_t*)nullptr, 1024, 512);
    hipLaunchKernelGGL(k_combine,   dim3(256), dim3(256), 0, stream, G, bc, slots, mng, mnb, s2f, snb);
    hipLaunchKernelGGL(k_gemm64<1>, dim3(16,4), dim3(256), 0, stream, snb, w1t,
                       b1, (const float*)nullptr, (float*)nullptr, h1b, 1024, 256);
    hipLaunchKernelGGL(k_gemm64<2>, dim3(4,4),  dim3(256), 0, stream, h1b, w2t,
                       b2, s2f, slots, (uint16_t*)nullptr, 256, 1024);
  }
}